// Round 1
// baseline (3381.491 us; speedup 1.0000x reference)
//
#include <hip/hip_runtime.h>

#define NJ 32
#define NE 1024
#define CD 128
#define HID 256
#define ROWS 8192
#define RB 32
#define BPJ (ROWS / RB) // 256 blocks per joint

struct Lv { int nj; int j[5]; int p[5]; };

// ---------------------------------------------------------------------------
// codebook norms: nrm[j*NE+n] = sum_c emb[j][n][c]^2   (4 lanes per code row)
// ---------------------------------------------------------------------------
__global__ __launch_bounds__(256) void norms_kernel(const float* __restrict__ emb,
                                                    float* __restrict__ nrm) {
  int gid = blockIdx.x * 256 + threadIdx.x;
  int n = gid >> 2, l = gid & 3;           // n in [0, NJ*NE)
  const float* row = emb + (size_t)n * CD;
  float s = 0.f;
#pragma unroll
  for (int i = 0; i < 8; ++i) {
    float4 v = *(const float4*)&row[(l + 4 * i) * 4];
    s += v.x * v.x + v.y * v.y + v.z * v.z + v.w * v.w;
  }
  s += __shfl_xor(s, 1);
  s += __shfl_xor(s, 2);
  if (l == 0) nrm[n] = s;
}

// ---------------------------------------------------------------------------
// fused per-level kernel: MLP (if non-root) + VQ for a 32-row tile of a joint
// thread layout: 256 threads, ti = tid>>4 (row pair), tj = tid&15 (col group)
// ---------------------------------------------------------------------------
__global__ __launch_bounds__(256) void fused_level(
    const float* __restrict__ z, const float* __restrict__ emb,
    const float* __restrict__ W1, const float* __restrict__ b1,
    const float* __restrict__ lng, const float* __restrict__ lnb,
    const float* __restrict__ W2, const float* __restrict__ b2,
    const float* __restrict__ nrm,
    float* __restrict__ zq, float* __restrict__ idx_out,
    float* __restrict__ partials, Lv lv, int pbase) {
  // LDS layout (floats):
  //   regA [0,8320)      : phase1 ws1[32][260]  /  phase2-3 as[32][257]
  //   regB [8320,10432)  : phase1 xs[32][34]    /  ws2,es [16][132]
  //   hs   [10432,14784) : h tile, [128][34] col-major
  //   nsm  [14784,14912) : codebook-norm chunk
  __shared__ __align__(16) float smem[14912];
  __shared__ float wsum[4];
  float* regA = smem;
  float* regB = smem + 8320;
  float* hs = smem + 10432;
  float* nsm = smem + 14784;

  const int tid = threadIdx.x;
  const int ti = tid >> 4, tj = tid & 15;
  const int jl = blockIdx.x / BPJ;
  const int row0 = (blockIdx.x % BPJ) * RB;
  const int jj = lv.j[jl], pj = lv.p[jl];
  const size_t rstride = (size_t)NJ * CD;

  if (pj >= 0) {
    // ---------------- phase 1: h1 = [e_parent | z_j] @ W1 ----------------
    float acc1[2][16];
#pragma unroll
    for (int i = 0; i < 16; ++i) { acc1[0][i] = 0.f; acc1[1][i] = 0.f; }
    float* xs = regB;   // [k=32][row 34-pad]
    float* ws1 = regA;  // [k=32][col 260-pad]
    const int rs = tid >> 3, kq = tid & 7;
    for (int ks = 0; ks < 8; ++ks) {
      const float* src = (ks < 4)
          ? (zq + (size_t)(row0 + rs) * rstride + (size_t)pj * CD + (ks * 32 + kq * 4))
          : (z + (size_t)(row0 + rs) * rstride + (size_t)jj * CD + (ks * 32 - 128 + kq * 4));
      float4 xv = *(const float4*)src;
      xs[(kq * 4 + 0) * 34 + rs] = xv.x;
      xs[(kq * 4 + 1) * 34 + rs] = xv.y;
      xs[(kq * 4 + 2) * 34 + rs] = xv.z;
      xs[(kq * 4 + 3) * 34 + rs] = xv.w;
#pragma unroll
      for (int i = 0; i < 8; ++i) {
        int c4 = kq + 8 * i;
        float4 wv = *(const float4*)&W1[(size_t)(ks * 32 + rs) * HID + c4 * 4];
        *(float4*)&ws1[rs * 260 + c4 * 4] = wv;
      }
      __syncthreads();
#pragma unroll
      for (int kk = 0; kk < 32; ++kk) {
        float2 xv2 = *(const float2*)&xs[kk * 34 + 2 * ti];
#pragma unroll
        for (int g = 0; g < 4; ++g) {
          float4 w = *(const float4*)&ws1[kk * 260 + g * 64 + tj * 4];
          acc1[0][g * 4 + 0] += xv2.x * w.x; acc1[0][g * 4 + 1] += xv2.x * w.y;
          acc1[0][g * 4 + 2] += xv2.x * w.z; acc1[0][g * 4 + 3] += xv2.x * w.w;
          acc1[1][g * 4 + 0] += xv2.y * w.x; acc1[1][g * 4 + 1] += xv2.y * w.y;
          acc1[1][g * 4 + 2] += xv2.y * w.z; acc1[1][g * 4 + 3] += xv2.y * w.w;
        }
      }
      __syncthreads();
    }
    // ---------------- phase 2: +b1, LayerNorm, ReLU -> as ----------------
    float* as = regA;  // [32][257]
    float s0 = 0, q0 = 0, s1 = 0, q1 = 0;
#pragma unroll
    for (int g = 0; g < 4; ++g) {
      float4 bv = *(const float4*)&b1[g * 64 + tj * 4];
      float bb[4] = {bv.x, bv.y, bv.z, bv.w};
#pragma unroll
      for (int cc = 0; cc < 4; ++cc) {
        float v0 = acc1[0][g * 4 + cc] + bb[cc];
        float v1 = acc1[1][g * 4 + cc] + bb[cc];
        acc1[0][g * 4 + cc] = v0; acc1[1][g * 4 + cc] = v1;
        s0 += v0; q0 += v0 * v0; s1 += v1; q1 += v1 * v1;
      }
    }
#pragma unroll
    for (int m = 1; m < 16; m <<= 1) {
      s0 += __shfl_xor(s0, m); q0 += __shfl_xor(q0, m);
      s1 += __shfl_xor(s1, m); q1 += __shfl_xor(q1, m);
    }
    float mu0 = s0 * (1.f / HID), mu1 = s1 * (1.f / HID);
    float va0 = q0 * (1.f / HID) - mu0 * mu0;
    float va1 = q1 * (1.f / HID) - mu1 * mu1;
    float iv0 = 1.f / sqrtf(va0 + 1e-5f);
    float iv1 = 1.f / sqrtf(va1 + 1e-5f);
#pragma unroll
    for (int g = 0; g < 4; ++g) {
      float4 gv = *(const float4*)&lng[g * 64 + tj * 4];
      float4 bv = *(const float4*)&lnb[g * 64 + tj * 4];
      float gg[4] = {gv.x, gv.y, gv.z, gv.w};
      float bb[4] = {bv.x, bv.y, bv.z, bv.w};
#pragma unroll
      for (int cc = 0; cc < 4; ++cc) {
        int c = g * 64 + tj * 4 + cc;
        float a0 = (acc1[0][g * 4 + cc] - mu0) * iv0 * gg[cc] + bb[cc];
        float a1 = (acc1[1][g * 4 + cc] - mu1) * iv1 * gg[cc] + bb[cc];
        as[(2 * ti) * 257 + c] = fmaxf(a0, 0.f);
        as[(2 * ti + 1) * 257 + c] = fmaxf(a1, 0.f);
      }
    }
    __syncthreads();
    // ---------------- phase 3: h = a @ W2 + b2 -> hs ----------------
    float acc2[2][8];
#pragma unroll
    for (int i = 0; i < 8; ++i) { acc2[0][i] = 0.f; acc2[1][i] = 0.f; }
    float* ws2 = regB;  // [16][132]
    for (int ks = 0; ks < 16; ++ks) {
#pragma unroll
      for (int u = 0; u < 2; ++u) {
        int idx = tid + u * 256;
        int kk = idx >> 5, c4 = idx & 31;
        float4 wv = *(const float4*)&W2[(size_t)(ks * 16 + kk) * CD + c4 * 4];
        *(float4*)&ws2[kk * 132 + c4 * 4] = wv;
      }
      __syncthreads();
#pragma unroll
      for (int kk = 0; kk < 16; ++kk) {
        int k = ks * 16 + kk;
        float a0 = as[(2 * ti) * 257 + k];
        float a1 = as[(2 * ti + 1) * 257 + k];
#pragma unroll
        for (int g = 0; g < 2; ++g) {
          float4 w = *(const float4*)&ws2[kk * 132 + g * 64 + tj * 4];
          acc2[0][g * 4 + 0] += a0 * w.x; acc2[0][g * 4 + 1] += a0 * w.y;
          acc2[0][g * 4 + 2] += a0 * w.z; acc2[0][g * 4 + 3] += a0 * w.w;
          acc2[1][g * 4 + 0] += a1 * w.x; acc2[1][g * 4 + 1] += a1 * w.y;
          acc2[1][g * 4 + 2] += a1 * w.z; acc2[1][g * 4 + 3] += a1 * w.w;
        }
      }
      __syncthreads();
    }
#pragma unroll
    for (int g = 0; g < 2; ++g) {
      float4 bv = *(const float4*)&b2[g * 64 + tj * 4];
      float bb[4] = {bv.x, bv.y, bv.z, bv.w};
#pragma unroll
      for (int cc = 0; cc < 4; ++cc) {
        int c = g * 64 + tj * 4 + cc;
        hs[c * 34 + 2 * ti] = acc2[0][g * 4 + cc] + bb[cc];
        hs[c * 34 + 2 * ti + 1] = acc2[1][g * 4 + cc] + bb[cc];
      }
    }
  } else {
    // root joint: h = z_j directly
#pragma unroll
    for (int u = 0; u < 4; ++u) {
      int idx = tid + u * 256;
      int r = idx >> 5, c4 = idx & 31;
      float4 v = *(const float4*)&z[(size_t)(row0 + r) * rstride + (size_t)jj * CD + c4 * 4];
      hs[(c4 * 4 + 0) * 34 + r] = v.x;
      hs[(c4 * 4 + 1) * 34 + r] = v.y;
      hs[(c4 * 4 + 2) * 34 + r] = v.z;
      hs[(c4 * 4 + 3) * 34 + r] = v.w;
    }
  }
  __syncthreads();

  // ---------------- phase 4: d = ||E||^2 - 2 h.E ; running argmin ----------
  float mnv0 = 3.402823e38f, mnv1 = 3.402823e38f;
  int mni0 = 0, mni1 = 0;
  const float* embJ = emb + (size_t)jj * NE * CD;
  const float* nrmJ = nrm + jj * NE;
  float* es = regB;  // [k=16][n 132-pad]
  for (int nb = 0; nb < 8; ++nb) {
    __syncthreads();  // protect nsm/regB WAR from previous chunk readers
    if (tid < 32) {
      float4 v = *(const float4*)&nrmJ[nb * 128 + tid * 4];
      *(float4*)&nsm[tid * 4] = v;
    }
    float acc4[2][8];
#pragma unroll
    for (int i = 0; i < 8; ++i) { acc4[0][i] = 0.f; acc4[1][i] = 0.f; }
    for (int ks = 0; ks < 8; ++ks) {
#pragma unroll
      for (int u = 0; u < 2; ++u) {
        int idx = tid + u * 256;
        int n = idx >> 2, k4 = idx & 3;
        float4 v = *(const float4*)&embJ[(size_t)(nb * 128 + n) * CD + ks * 16 + k4 * 4];
        es[(k4 * 4 + 0) * 132 + n] = v.x;
        es[(k4 * 4 + 1) * 132 + n] = v.y;
        es[(k4 * 4 + 2) * 132 + n] = v.z;
        es[(k4 * 4 + 3) * 132 + n] = v.w;
      }
      __syncthreads();
#pragma unroll
      for (int kk = 0; kk < 16; ++kk) {
        int k = ks * 16 + kk;
        float2 hv = *(const float2*)&hs[k * 34 + 2 * ti];
#pragma unroll
        for (int g = 0; g < 2; ++g) {
          float4 e4 = *(const float4*)&es[kk * 132 + g * 64 + tj * 4];
          acc4[0][g * 4 + 0] += hv.x * e4.x; acc4[0][g * 4 + 1] += hv.x * e4.y;
          acc4[0][g * 4 + 2] += hv.x * e4.z; acc4[0][g * 4 + 3] += hv.x * e4.w;
          acc4[1][g * 4 + 0] += hv.y * e4.x; acc4[1][g * 4 + 1] += hv.y * e4.y;
          acc4[1][g * 4 + 2] += hv.y * e4.z; acc4[1][g * 4 + 3] += hv.y * e4.w;
        }
      }
      __syncthreads();
    }
    // min update, ascending-n scan order with strict < (first-occurrence tie)
#pragma unroll
    for (int g = 0; g < 2; ++g) {
#pragma unroll
      for (int cc = 0; cc < 4; ++cc) {
        int nl = g * 64 + tj * 4 + cc;
        float base = nsm[nl];
        float d0 = base - 2.f * acc4[0][g * 4 + cc];
        float d1 = base - 2.f * acc4[1][g * 4 + cc];
        int n = nb * 128 + nl;
        if (d0 < mnv0) { mnv0 = d0; mni0 = n; }
        if (d1 < mnv1) { mnv1 = d1; mni1 = n; }
      }
    }
  }
  // cross-lane argmin reduce (16 lanes per row), tie -> smaller index
#pragma unroll
  for (int m = 1; m < 16; m <<= 1) {
    float om0 = __shfl_xor(mnv0, m); int oi0 = __shfl_xor(mni0, m);
    float om1 = __shfl_xor(mnv1, m); int oi1 = __shfl_xor(mni1, m);
    if (om0 < mnv0 || (om0 == mnv0 && oi0 < mni0)) { mnv0 = om0; mni0 = oi0; }
    if (om1 < mnv1 || (om1 == mnv1 && oi1 < mni1)) { mnv1 = om1; mni1 = oi1; }
  }
  // gather e, write z_q + indices, accumulate loss
  float lsum = 0.f;
#pragma unroll
  for (int rr = 0; rr < 2; ++rr) {
    int r = 2 * ti + rr;
    int id = rr ? mni1 : mni0;
    const float* erow = embJ + (size_t)id * CD;
    float* orow = zq + (size_t)(row0 + r) * rstride + (size_t)jj * CD;
#pragma unroll
    for (int q = 0; q < 2; ++q) {
      int c0 = tj * 8 + q * 4;
      float4 ev = *(const float4*)&erow[c0];
      float h0 = hs[(c0 + 0) * 34 + r];
      float h1 = hs[(c0 + 1) * 34 + r];
      float h2 = hs[(c0 + 2) * 34 + r];
      float h3 = hs[(c0 + 3) * 34 + r];
      float dx = ev.x - h0, dy = ev.y - h1, dz = ev.z - h2, dw = ev.w - h3;
      lsum += dx * dx + dy * dy + dz * dz + dw * dw;
      *(float4*)&orow[c0] = ev;
    }
    if (tj == 0) idx_out[(size_t)(row0 + r) * NJ + jj] = (float)id;
  }
#pragma unroll
  for (int m = 1; m < 64; m <<= 1) lsum += __shfl_xor(lsum, m);
  if ((tid & 63) == 0) wsum[tid >> 6] = lsum;
  __syncthreads();
  if (tid == 0) partials[pbase + blockIdx.x] = wsum[0] + wsum[1] + wsum[2] + wsum[3];
}

// ---------------------------------------------------------------------------
// deterministic loss reduction
// ---------------------------------------------------------------------------
__global__ __launch_bounds__(256) void loss_reduce(const float* __restrict__ p, int n,
                                                   float* __restrict__ out) {
  __shared__ float ws[4];
  float s = 0.f;
  for (int i = threadIdx.x; i < n; i += 256) s += p[i];
#pragma unroll
  for (int m = 1; m < 64; m <<= 1) s += __shfl_xor(s, m);
  if ((threadIdx.x & 63) == 0) ws[threadIdx.x >> 6] = s;
  __syncthreads();
  if (threadIdx.x == 0)
    out[0] = (ws[0] + ws[1] + ws[2] + ws[3]) * (1.25f / (1048576.f * 32.f));
}

extern "C" void kernel_launch(void* const* d_in, const int* in_sizes, int n_in,
                              void* d_out, int out_size, void* d_ws, size_t ws_size,
                              hipStream_t stream) {
  const float* z = (const float*)d_in[0];
  const float* emb = (const float*)d_in[1];
  const float* W1 = (const float*)d_in[2];
  const float* b1 = (const float*)d_in[3];
  const float* lng = (const float*)d_in[4];
  const float* lnb = (const float*)d_in[5];
  const float* W2 = (const float*)d_in[6];
  const float* b2 = (const float*)d_in[7];

  float* zq = (float*)d_out;
  float* loss = zq + (size_t)ROWS * NJ * CD;  // 33,554,432
  float* idxo = loss + 1;

  float* nrm = (float*)d_ws;           // NJ*NE floats
  float* partials = nrm + NJ * NE;     // 32*256 floats

  norms_kernel<<<NJ * NE * 4 / 256, 256, 0, stream>>>(emb, nrm);

  static const Lv levels[11] = {
      {1, {0, 0, 0, 0, 0}, {-1, 0, 0, 0, 0}},
      {3, {1, 6, 11, 0, 0}, {0, 0, 0, 0, 0}},
      {3, {2, 7, 12, 0, 0}, {1, 6, 11, 0, 0}},
      {5, {3, 8, 13, 16, 24}, {2, 7, 12, 12, 12}},
      {5, {4, 9, 14, 17, 25}, {3, 8, 13, 16, 24}},
      {5, {5, 10, 15, 18, 26}, {4, 9, 14, 17, 25}},
      {2, {19, 27, 0, 0, 0}, {18, 26, 0, 0, 0}},
      {2, {20, 28, 0, 0, 0}, {19, 27, 0, 0, 0}},
      {2, {21, 29, 0, 0, 0}, {20, 28, 0, 0, 0}},
      {2, {22, 30, 0, 0, 0}, {21, 29, 0, 0, 0}},
      {2, {23, 31, 0, 0, 0}, {22, 30, 0, 0, 0}},
  };

  int pbase = 0;
  for (int L = 0; L < 11; ++L) {
    fused_level<<<levels[L].nj * BPJ, 256, 0, stream>>>(
        z, emb, W1, b1, lng, lnb, W2, b2, nrm, zq, idxo, partials, levels[L], pbase);
    pbase += levels[L].nj * BPJ;
  }
  loss_reduce<<<1, 256, 0, stream>>>(partials, pbase, loss);
}

// Round 3
// 2064.308 us; speedup vs baseline: 1.6381x; 1.6381x over previous
//
#include <hip/hip_runtime.h>

#define NJ 32
#define NE 1024
#define CD 128
#define HID 256
#define ROWS 8192
#define RB 64
#define BPJ (ROWS / RB)   // 128 blocks per joint

struct Lv { int nj; int j[5]; int p[5]; };

// ---------------------------------------------------------------------------
// codebook norms: nrm[j*NE+n] = sum_c emb[j][n][c]^2   (4 lanes per code row)
// ---------------------------------------------------------------------------
__global__ __launch_bounds__(256) void norms_kernel(const float* __restrict__ emb,
                                                    float* __restrict__ nrm) {
  int gid = blockIdx.x * 256 + threadIdx.x;
  int n = gid >> 2, l = gid & 3;           // n in [0, NJ*NE)
  const float* row = emb + (size_t)n * CD;
  float s = 0.f;
#pragma unroll
  for (int i = 0; i < 8; ++i) {
    float4 v = *(const float4*)&row[(l + 4 * i) * 4];
    s += v.x * v.x + v.y * v.y + v.z * v.z + v.w * v.w;
  }
  s += __shfl_xor(s, 1);
  s += __shfl_xor(s, 2);
  if (l == 0) nrm[n] = s;
}

// ---------------------------------------------------------------------------
// fused per-level kernel, RB=64 rows per block, 8x8 register tiles.
// thread layout: rg = tid>>5 (8 row-groups of 8 rows), cg = tid&31.
// GEMM1/LN col ownership (round-1 bit-exact LN): u=cg&15, b=cg>>4;
//   thread owns cols {b*128+u*4 .. +3} and {b*128+64+u*4 .. +3}.
// LDS (floats): hs [0,8704) = h tile [128 dims][68 rows]
//               S  [8704,19520) scratch:
//                 phase1: xs [32][68] @S, ws1 [32][264] @S+2176
//                 phase3: as_ [128][68] @S, ws2 [16][132] @S+8704
//                 phase4: es [16][260] @S, nsm [256] @S+4160
// ---------------------------------------------------------------------------
__global__ __launch_bounds__(256) void fused_level(
    const float* __restrict__ z, const float* __restrict__ emb,
    const float* __restrict__ W1, const float* __restrict__ b1,
    const float* __restrict__ lng, const float* __restrict__ lnb,
    const float* __restrict__ W2, const float* __restrict__ b2,
    const float* __restrict__ nrm,
    float* __restrict__ zq, float* __restrict__ idx_out,
    float* __restrict__ partials, Lv lv, int pbase) {
  __shared__ __align__(16) float smem[19520];
  __shared__ float wsum[4];
  float* hs  = smem;
  float* S   = smem + 8704;
  float* xs  = S;
  float* ws1 = S + 2176;
  float* as_ = S;
  float* ws2 = S + 8704;
  float* es  = S;
  float* nsm = S + 4160;

  const int tid = threadIdx.x;
  const int rg = tid >> 5, cg = tid & 31;
  const int u = cg & 15;                       // round-1 "tj"
  const int qcA = (cg >> 4) * 128 + u * 4;     // first owned quad (col)
  const int qcB = qcA + 64;                    // second owned quad (col)
  const int jl = blockIdx.x / BPJ;
  const int row0 = (blockIdx.x % BPJ) * RB;
  const int jj = lv.j[jl], pj = lv.p[jl];
  const size_t rstride = (size_t)NJ * CD;

  if (pj >= 0) {
    // ================= phase 1: a1 = [e_parent | z_j] @ W1 =================
    float acc1[8][8];
#pragma unroll
    for (int r = 0; r < 8; ++r)
#pragma unroll
      for (int c = 0; c < 8; ++c) acc1[r][c] = 0.f;

#pragma unroll 1
    for (int ks = 0; ks < 8; ++ks) {
      // stage x chunk [32 k][64 rows] (transposed into xs)
#pragma unroll
      for (int uu = 0; uu < 2; ++uu) {
        int idx = uu * 256 + tid;
        int r = idx >> 3, kq = idx & 7;
        const float* src = (ks < 4)
            ? (zq + (size_t)(row0 + r) * rstride + (size_t)pj * CD + (ks * 32 + kq * 4))
            : (z  + (size_t)(row0 + r) * rstride + (size_t)jj * CD + (ks * 32 - 128 + kq * 4));
        float4 v = *(const float4*)src;
        xs[(kq * 4 + 0) * 68 + r] = v.x;
        xs[(kq * 4 + 1) * 68 + r] = v.y;
        xs[(kq * 4 + 2) * 68 + r] = v.z;
        xs[(kq * 4 + 3) * 68 + r] = v.w;
      }
      // stage W1 chunk [32 k][256 cols]
#pragma unroll
      for (int v8 = 0; v8 < 8; ++v8) {
        int idx = v8 * 256 + tid;
        int k = idx >> 6, c4 = idx & 63;
        *(float4*)&ws1[k * 264 + c4 * 4] =
            *(const float4*)&W1[(size_t)(ks * 32 + k) * HID + c4 * 4];
      }
      __syncthreads();
#pragma unroll 2
      for (int kk = 0; kk < 32; ++kk) {
        float xr[8], wc[8];
        *(float4*)&xr[0] = *(const float4*)&xs[kk * 68 + rg * 8];
        *(float4*)&xr[4] = *(const float4*)&xs[kk * 68 + rg * 8 + 4];
        *(float4*)&wc[0] = *(const float4*)&ws1[kk * 264 + qcA];
        *(float4*)&wc[4] = *(const float4*)&ws1[kk * 264 + qcB];
#pragma unroll
        for (int r = 0; r < 8; ++r)
#pragma unroll
          for (int c = 0; c < 8; ++c)
            acc1[r][c] += xr[r] * wc[c];
      }
      __syncthreads();
    }

    // ====== phase 2: +b1, LayerNorm, ReLU — round-1 bit-exact tree =========
    {
      float bb[8], gg[8], be[8];
      *(float4*)&bb[0] = *(const float4*)&b1[qcA];
      *(float4*)&bb[4] = *(const float4*)&b1[qcB];
      *(float4*)&gg[0] = *(const float4*)&lng[qcA];
      *(float4*)&gg[4] = *(const float4*)&lng[qcB];
      *(float4*)&be[0] = *(const float4*)&lnb[qcA];
      *(float4*)&be[4] = *(const float4*)&lnb[qcB];
#pragma unroll
      for (int r = 0; r < 8; ++r) {
        // b0 lane (cg<16): chain over g=0,1 quads starting from 0.
        float s0 = 0.f, q0 = 0.f;
#pragma unroll
        for (int j = 0; j < 8; ++j) {
          float v = acc1[r][j] + bb[j];
          acc1[r][j] = v;
          s0 += v; q0 += v * v;
        }
        // hand partial to b1 partner; b1 continues the chain over g=2,3.
        float si = __shfl_xor(s0, 16), qi = __shfl_xor(q0, 16);
        float s1 = si, q1 = qi;
#pragma unroll
        for (int j = 0; j < 8; ++j) {
          float v = acc1[r][j];
          s1 += v; q1 += v * v;
        }
        // round-1 butterfly over the 16 "tj" lanes (valid in b1 lanes)
#pragma unroll
        for (int m = 1; m < 16; m <<= 1) {
          s1 += __shfl_xor(s1, m); q1 += __shfl_xor(q1, m);
        }
        float s2 = __shfl_xor(s1, 16), q2 = __shfl_xor(q1, 16);
        float Sx = (cg & 16) ? s1 : s2;
        float Qx = (cg & 16) ? q1 : q2;
        float mu = Sx * (1.f / HID);
        float va = Qx * (1.f / HID) - mu * mu;
        float iv = 1.f / sqrtf(va + 1e-5f);
#pragma unroll
        for (int j = 0; j < 8; ++j) {
          float a = (acc1[r][j] - mu) * iv * gg[j] + be[j];
          acc1[r][j] = fmaxf(a, 0.f);
        }
      }
    }

    // ================= phase 3: h = a @ W2 + b2 (two 128-k halves) =========
    float acc2[8][4];
#pragma unroll
    for (int r = 0; r < 8; ++r)
#pragma unroll
      for (int c = 0; c < 4; ++c) acc2[r][c] = 0.f;

#pragma unroll 1
    for (int half = 0; half < 2; ++half) {
      __syncthreads();
      if ((cg >> 4) == half) {
#pragma unroll
        for (int j = 0; j < 8; ++j) {
          int kl = (j >> 2) * 64 + u * 4 + (j & 3);
          *(float4*)&as_[kl * 68 + rg * 8] =
              make_float4(acc1[0][j], acc1[1][j], acc1[2][j], acc1[3][j]);
          *(float4*)&as_[kl * 68 + rg * 8 + 4] =
              make_float4(acc1[4][j], acc1[5][j], acc1[6][j], acc1[7][j]);
        }
      }
      __syncthreads();
#pragma unroll 1
      for (int kc = 0; kc < 8; ++kc) {
#pragma unroll
        for (int v = 0; v < 2; ++v) {
          int idx = v * 256 + tid;
          int k = idx >> 5, c4 = idx & 31;
          *(float4*)&ws2[k * 132 + c4 * 4] =
              *(const float4*)&W2[(size_t)(half * 128 + kc * 16 + k) * CD + c4 * 4];
        }
        __syncthreads();
#pragma unroll 2
        for (int kk = 0; kk < 16; ++kk) {
          float ar[8], wc2[4];
          *(float4*)&ar[0] = *(const float4*)&as_[(kc * 16 + kk) * 68 + rg * 8];
          *(float4*)&ar[4] = *(const float4*)&as_[(kc * 16 + kk) * 68 + rg * 8 + 4];
          *(float4*)&wc2[0] = *(const float4*)&ws2[kk * 132 + cg * 4];
#pragma unroll
          for (int r = 0; r < 8; ++r)
#pragma unroll
            for (int c = 0; c < 4; ++c)
              acc2[r][c] += ar[r] * wc2[c];
        }
        __syncthreads();
      }
    }
    {
      float4 bv = *(const float4*)&b2[cg * 4];
      float bb2[4] = {bv.x, bv.y, bv.z, bv.w};
#pragma unroll
      for (int c = 0; c < 4; ++c) {
        float4 lo = make_float4(acc2[0][c] + bb2[c], acc2[1][c] + bb2[c],
                                acc2[2][c] + bb2[c], acc2[3][c] + bb2[c]);
        float4 hi = make_float4(acc2[4][c] + bb2[c], acc2[5][c] + bb2[c],
                                acc2[6][c] + bb2[c], acc2[7][c] + bb2[c]);
        *(float4*)&hs[(cg * 4 + c) * 68 + rg * 8] = lo;
        *(float4*)&hs[(cg * 4 + c) * 68 + rg * 8 + 4] = hi;
      }
    }
  } else {
    // root joint: h = z_j directly
#pragma unroll
    for (int v = 0; v < 8; ++v) {
      int idx = v * 256 + tid;
      int r = idx >> 5, c4 = idx & 31;
      float4 vz = *(const float4*)&z[(size_t)(row0 + r) * rstride + (size_t)jj * CD + c4 * 4];
      hs[(c4 * 4 + 0) * 68 + r] = vz.x;
      hs[(c4 * 4 + 1) * 68 + r] = vz.y;
      hs[(c4 * 4 + 2) * 68 + r] = vz.z;
      hs[(c4 * 4 + 3) * 68 + r] = vz.w;
    }
  }

  // ================= phase 4: d = ||E||^2 - 2 h.E ; running argmin =========
  float mnv[8]; int mni[8];
#pragma unroll
  for (int r = 0; r < 8; ++r) { mnv[r] = 3.402823e38f; mni[r] = 0; }
  const float* embJ = emb + (size_t)jj * NE * CD;
  const float* nrmJ = nrm + jj * NE;

#pragma unroll 1
  for (int p = 0; p < 4; ++p) {
    __syncthreads();  // hs ready (p=0); es/nsm WAR from previous chunk
    if (tid < 64) {
      *(float4*)&nsm[tid * 4] = *(const float4*)&nrmJ[p * 256 + tid * 4];
    }
    float acc4[8][8];
#pragma unroll
    for (int r = 0; r < 8; ++r)
#pragma unroll
      for (int c = 0; c < 8; ++c) acc4[r][c] = 0.f;

#pragma unroll 1
    for (int kc = 0; kc < 8; ++kc) {
      // stage e chunk [16 dims][256 codes] (coalesced 64B per 4 lanes)
#pragma unroll
      for (int v = 0; v < 4; ++v) {
        int idx = v * 256 + tid;
        int n = idx >> 2, kq = idx & 3;
        float4 ev = *(const float4*)&embJ[(size_t)(p * 256 + n) * CD + kc * 16 + kq * 4];
        es[(kq * 4 + 0) * 260 + n] = ev.x;
        es[(kq * 4 + 1) * 260 + n] = ev.y;
        es[(kq * 4 + 2) * 260 + n] = ev.z;
        es[(kq * 4 + 3) * 260 + n] = ev.w;
      }
      __syncthreads();
#pragma unroll 2
      for (int kk = 0; kk < 16; ++kk) {
        int c = kc * 16 + kk;
        float hr[8], ec[8];
        *(float4*)&hr[0] = *(const float4*)&hs[c * 68 + rg * 8];
        *(float4*)&hr[4] = *(const float4*)&hs[c * 68 + rg * 8 + 4];
        *(float4*)&ec[0] = *(const float4*)&es[kk * 260 + cg * 8];
        *(float4*)&ec[4] = *(const float4*)&es[kk * 260 + cg * 8 + 4];
#pragma unroll
        for (int r = 0; r < 8; ++r)
#pragma unroll
          for (int c2 = 0; c2 < 8; ++c2)
            acc4[r][c2] += hr[r] * ec[c2];
      }
      __syncthreads();
    }
    // min update, ascending-n order with strict < (first-occurrence ties)
#pragma unroll
    for (int r = 0; r < 8; ++r) {
#pragma unroll
      for (int j2 = 0; j2 < 8; ++j2) {
        float d = nsm[cg * 8 + j2] - 2.f * acc4[r][j2];
        int n = p * 256 + cg * 8 + j2;
        if (d < mnv[r]) { mnv[r] = d; mni[r] = n; }
      }
    }
  }

  // cross-lane argmin reduce over the 32-lane col group, tie -> smaller index
#pragma unroll
  for (int r = 0; r < 8; ++r) {
    float mv = mnv[r]; int mi = mni[r];
#pragma unroll
    for (int m = 1; m < 32; m <<= 1) {
      float om = __shfl_xor(mv, m); int oi = __shfl_xor(mi, m);
      if (om < mv || (om == mv && oi < mi)) { mv = om; mi = oi; }
    }
    mnv[r] = mv; mni[r] = mi;
  }

  // gather e, write z_q + indices, accumulate loss
  float lsum = 0.f;
#pragma unroll
  for (int r = 0; r < 8; ++r) {
    int row = rg * 8 + r;
    int id = mni[r];
    const float* erow = embJ + (size_t)id * CD;
    float4 ev = *(const float4*)&erow[cg * 4];
    float h0 = hs[(cg * 4 + 0) * 68 + row];
    float h1 = hs[(cg * 4 + 1) * 68 + row];
    float h2 = hs[(cg * 4 + 2) * 68 + row];
    float h3 = hs[(cg * 4 + 3) * 68 + row];
    float dx = ev.x - h0, dy = ev.y - h1, dz = ev.z - h2, dw = ev.w - h3;
    lsum += dx * dx + dy * dy + dz * dz + dw * dw;
    *(float4*)&zq[(size_t)(row0 + row) * rstride + (size_t)jj * CD + cg * 4] = ev;
    if (cg == 0) idx_out[(size_t)(row0 + row) * NJ + jj] = (float)id;
  }
#pragma unroll
  for (int m = 1; m < 64; m <<= 1) lsum += __shfl_xor(lsum, m);
  if ((tid & 63) == 0) wsum[tid >> 6] = lsum;
  __syncthreads();
  if (tid == 0) partials[pbase + blockIdx.x] = wsum[0] + wsum[1] + wsum[2] + wsum[3];
}

// ---------------------------------------------------------------------------
// deterministic loss reduction
// ---------------------------------------------------------------------------
__global__ __launch_bounds__(256) void loss_reduce(const float* __restrict__ p, int n,
                                                   float* __restrict__ out) {
  __shared__ float ws[4];
  float s = 0.f;
  for (int i = threadIdx.x; i < n; i += 256) s += p[i];
#pragma unroll
  for (int m = 1; m < 64; m <<= 1) s += __shfl_xor(s, m);
  if ((threadIdx.x & 63) == 0) ws[threadIdx.x >> 6] = s;
  __syncthreads();
  if (threadIdx.x == 0)
    out[0] = (ws[0] + ws[1] + ws[2] + ws[3]) * (1.25f / (1048576.f * 32.f));
}

extern "C" void kernel_launch(void* const* d_in, const int* in_sizes, int n_in,
                              void* d_out, int out_size, void* d_ws, size_t ws_size,
                              hipStream_t stream) {
  const float* z = (const float*)d_in[0];
  const float* emb = (const float*)d_in[1];
  const float* W1 = (const float*)d_in[2];
  const float* b1 = (const float*)d_in[3];
  const float* lng = (const float*)d_in[4];
  const float* lnb = (const float*)d_in[5];
  const float* W2 = (const float*)d_in[6];
  const float* b2 = (const float*)d_in[7];

  float* zq = (float*)d_out;
  float* loss = zq + (size_t)ROWS * NJ * CD;  // 33,554,432
  float* idxo = loss + 1;

  float* nrm = (float*)d_ws;           // NJ*NE floats
  float* partials = nrm + NJ * NE;     // 32*128 floats

  norms_kernel<<<NJ * NE * 4 / 256, 256, 0, stream>>>(emb, nrm);

  static const Lv levels[11] = {
      {1, {0, 0, 0, 0, 0}, {-1, 0, 0, 0, 0}},
      {3, {1, 6, 11, 0, 0}, {0, 0, 0, 0, 0}},
      {3, {2, 7, 12, 0, 0}, {1, 6, 11, 0, 0}},
      {5, {3, 8, 13, 16, 24}, {2, 7, 12, 12, 12}},
      {5, {4, 9, 14, 17, 25}, {3, 8, 13, 16, 24}},
      {5, {5, 10, 15, 18, 26}, {4, 9, 14, 17, 25}},
      {2, {19, 27, 0, 0, 0}, {18, 26, 0, 0, 0}},
      {2, {20, 28, 0, 0, 0}, {19, 27, 0, 0, 0}},
      {2, {21, 29, 0, 0, 0}, {20, 28, 0, 0, 0}},
      {2, {22, 30, 0, 0, 0}, {21, 29, 0, 0, 0}},
      {2, {23, 31, 0, 0, 0}, {22, 30, 0, 0, 0}},
  };

  int pbase = 0;
  for (int L = 0; L < 11; ++L) {
    fused_level<<<levels[L].nj * BPJ, 256, 0, stream>>>(
        z, emb, W1, b1, lng, lnb, W2, b2, nrm, zq, idxo, partials, levels[L], pbase);
    pbase += levels[L].nj * BPJ;
  }
  loss_reduce<<<1, 256, 0, stream>>>(partials, pbase, loss);
}

// Round 4
// 2050.448 us; speedup vs baseline: 1.6491x; 1.0068x over previous
//
#include <hip/hip_runtime.h>

#define NJ 32
#define NE 1024
#define CD 128
#define HID 256
#define ROWS 8192
#define RB 64
#define BPJ (ROWS / RB)   // 128 blocks per joint

struct Lv { int nj; int j[5]; int p[5]; };

// ---------------------------------------------------------------------------
// codebook norms: nrm[j*NE+n] = sum_c emb[j][n][c]^2   (4 lanes per code row)
// ---------------------------------------------------------------------------
__global__ __launch_bounds__(256) void norms_kernel(const float* __restrict__ emb,
                                                    float* __restrict__ nrm) {
  int gid = blockIdx.x * 256 + threadIdx.x;
  int n = gid >> 2, l = gid & 3;           // n in [0, NJ*NE)
  const float* row = emb + (size_t)n * CD;
  float s = 0.f;
#pragma unroll
  for (int i = 0; i < 8; ++i) {
    float4 v = *(const float4*)&row[(l + 4 * i) * 4];
    s += v.x * v.x + v.y * v.y + v.z * v.z + v.w * v.w;
  }
  s += __shfl_xor(s, 1);
  s += __shfl_xor(s, 2);
  if (l == 0) nrm[n] = s;
}

// ---------------------------------------------------------------------------
// fused per-level kernel, RB=64 rows per block, 8x8 register tiles.
// thread layout: rg = tid>>5 (8 row-groups of 8 rows), cg = tid&31.
// col/code ownership (contiguous-16B-chunk, conflict-free): u=cg&15, b=cg>>4;
//   thread owns cols/codes {b*128+u*4 .. +3} and {b*128+64+u*4 .. +3}.
// LDS (floats): hs [0,8704) = h tile [128 dims][68 rows]
//               S  [8704,19520) scratch:
//                 phase1: xs [32][68] @S, ws1 [32][264] @S+2176
//                 phase3: as_ [128][68] @S, ws2 [16][132] @S+8704
//                 phase4: es [16][260] @S, nsm [256] @S+4160
// ---------------------------------------------------------------------------
__global__ __launch_bounds__(256) void fused_level(
    const float* __restrict__ z, const float* __restrict__ emb,
    const float* __restrict__ W1, const float* __restrict__ b1,
    const float* __restrict__ lng, const float* __restrict__ lnb,
    const float* __restrict__ W2, const float* __restrict__ b2,
    const float* __restrict__ nrm,
    float* __restrict__ zq, float* __restrict__ idx_out,
    float* __restrict__ partials, Lv lv, int pbase) {
  __shared__ __align__(16) float smem[19520];
  __shared__ float wsum[4];
  float* hs  = smem;
  float* S   = smem + 8704;
  float* xs  = S;
  float* ws1 = S + 2176;
  float* as_ = S;
  float* ws2 = S + 8704;
  float* es  = S;
  float* nsm = S + 4160;

  const int tid = threadIdx.x;
  const int rg = tid >> 5, cg = tid & 31;
  const int u = cg & 15;                       // round-1 "tj"
  const int qcA = (cg >> 4) * 128 + u * 4;     // first owned quad (col/code)
  const int qcB = qcA + 64;                    // second owned quad (col/code)
  const int jl = blockIdx.x / BPJ;
  const int row0 = (blockIdx.x % BPJ) * RB;
  const int jj = lv.j[jl], pj = lv.p[jl];
  const size_t rstride = (size_t)NJ * CD;

  if (pj >= 0) {
    // ================= phase 1: a1 = [e_parent | z_j] @ W1 =================
    float acc1[8][8];
#pragma unroll
    for (int r = 0; r < 8; ++r)
#pragma unroll
      for (int c = 0; c < 8; ++c) acc1[r][c] = 0.f;

#pragma unroll 1
    for (int ks = 0; ks < 8; ++ks) {
      // stage x chunk [32 k][64 rows] (transposed into xs)
#pragma unroll
      for (int uu = 0; uu < 2; ++uu) {
        int idx = uu * 256 + tid;
        int r = idx >> 3, kq = idx & 7;
        const float* src = (ks < 4)
            ? (zq + (size_t)(row0 + r) * rstride + (size_t)pj * CD + (ks * 32 + kq * 4))
            : (z  + (size_t)(row0 + r) * rstride + (size_t)jj * CD + (ks * 32 - 128 + kq * 4));
        float4 v = *(const float4*)src;
        xs[(kq * 4 + 0) * 68 + r] = v.x;
        xs[(kq * 4 + 1) * 68 + r] = v.y;
        xs[(kq * 4 + 2) * 68 + r] = v.z;
        xs[(kq * 4 + 3) * 68 + r] = v.w;
      }
      // stage W1 chunk [32 k][256 cols]
#pragma unroll
      for (int v8 = 0; v8 < 8; ++v8) {
        int idx = v8 * 256 + tid;
        int k = idx >> 6, c4 = idx & 63;
        *(float4*)&ws1[k * 264 + c4 * 4] =
            *(const float4*)&W1[(size_t)(ks * 32 + k) * HID + c4 * 4];
      }
      __syncthreads();
#pragma unroll 2
      for (int kk = 0; kk < 32; ++kk) {
        float xr[8], wc[8];
        *(float4*)&xr[0] = *(const float4*)&xs[kk * 68 + rg * 8];
        *(float4*)&xr[4] = *(const float4*)&xs[kk * 68 + rg * 8 + 4];
        *(float4*)&wc[0] = *(const float4*)&ws1[kk * 264 + qcA];
        *(float4*)&wc[4] = *(const float4*)&ws1[kk * 264 + qcB];
#pragma unroll
        for (int r = 0; r < 8; ++r)
#pragma unroll
          for (int c = 0; c < 8; ++c)
            acc1[r][c] += xr[r] * wc[c];
      }
      __syncthreads();
    }

    // ====== phase 2: +b1, LayerNorm, ReLU — round-1 bit-exact tree =========
    {
      float bb[8], gg[8], be[8];
      *(float4*)&bb[0] = *(const float4*)&b1[qcA];
      *(float4*)&bb[4] = *(const float4*)&b1[qcB];
      *(float4*)&gg[0] = *(const float4*)&lng[qcA];
      *(float4*)&gg[4] = *(const float4*)&lng[qcB];
      *(float4*)&be[0] = *(const float4*)&lnb[qcA];
      *(float4*)&be[4] = *(const float4*)&lnb[qcB];
#pragma unroll
      for (int r = 0; r < 8; ++r) {
        // b0 lane (cg<16): chain over g=0,1 quads starting from 0.
        float s0 = 0.f, q0 = 0.f;
#pragma unroll
        for (int j = 0; j < 8; ++j) {
          float v = acc1[r][j] + bb[j];
          acc1[r][j] = v;
          s0 += v; q0 += v * v;
        }
        // hand partial to b1 partner; b1 continues the chain over g=2,3.
        float si = __shfl_xor(s0, 16), qi = __shfl_xor(q0, 16);
        float s1 = si, q1 = qi;
#pragma unroll
        for (int j = 0; j < 8; ++j) {
          float v = acc1[r][j];
          s1 += v; q1 += v * v;
        }
        // round-1 butterfly over the 16 "tj" lanes (valid in b1 lanes)
#pragma unroll
        for (int m = 1; m < 16; m <<= 1) {
          s1 += __shfl_xor(s1, m); q1 += __shfl_xor(q1, m);
        }
        float s2 = __shfl_xor(s1, 16), q2 = __shfl_xor(q1, 16);
        float Sx = (cg & 16) ? s1 : s2;
        float Qx = (cg & 16) ? q1 : q2;
        float mu = Sx * (1.f / HID);
        float va = Qx * (1.f / HID) - mu * mu;
        float iv = 1.f / sqrtf(va + 1e-5f);
#pragma unroll
        for (int j = 0; j < 8; ++j) {
          float a = (acc1[r][j] - mu) * iv * gg[j] + be[j];
          acc1[r][j] = fmaxf(a, 0.f);
        }
      }
    }

    // ================= phase 3: h = a @ W2 + b2 (two 128-k halves) =========
    float acc2[8][4];
#pragma unroll
    for (int r = 0; r < 8; ++r)
#pragma unroll
      for (int c = 0; c < 4; ++c) acc2[r][c] = 0.f;

#pragma unroll 1
    for (int half = 0; half < 2; ++half) {
      __syncthreads();
      if ((cg >> 4) == half) {
#pragma unroll
        for (int j = 0; j < 8; ++j) {
          int kl = (j >> 2) * 64 + u * 4 + (j & 3);
          *(float4*)&as_[kl * 68 + rg * 8] =
              make_float4(acc1[0][j], acc1[1][j], acc1[2][j], acc1[3][j]);
          *(float4*)&as_[kl * 68 + rg * 8 + 4] =
              make_float4(acc1[4][j], acc1[5][j], acc1[6][j], acc1[7][j]);
        }
      }
      __syncthreads();
#pragma unroll 1
      for (int kc = 0; kc < 8; ++kc) {
#pragma unroll
        for (int v = 0; v < 2; ++v) {
          int idx = v * 256 + tid;
          int k = idx >> 5, c4 = idx & 31;
          *(float4*)&ws2[k * 132 + c4 * 4] =
              *(const float4*)&W2[(size_t)(half * 128 + kc * 16 + k) * CD + c4 * 4];
        }
        __syncthreads();
#pragma unroll 2
        for (int kk = 0; kk < 16; ++kk) {
          float ar[8], wc2[4];
          *(float4*)&ar[0] = *(const float4*)&as_[(kc * 16 + kk) * 68 + rg * 8];
          *(float4*)&ar[4] = *(const float4*)&as_[(kc * 16 + kk) * 68 + rg * 8 + 4];
          *(float4*)&wc2[0] = *(const float4*)&ws2[kk * 132 + cg * 4];
#pragma unroll
          for (int r = 0; r < 8; ++r)
#pragma unroll
            for (int c = 0; c < 4; ++c)
              acc2[r][c] += ar[r] * wc2[c];
        }
        __syncthreads();
      }
    }
    {
      float4 bv = *(const float4*)&b2[cg * 4];
      float bb2[4] = {bv.x, bv.y, bv.z, bv.w};
#pragma unroll
      for (int c = 0; c < 4; ++c) {
        float4 lo = make_float4(acc2[0][c] + bb2[c], acc2[1][c] + bb2[c],
                                acc2[2][c] + bb2[c], acc2[3][c] + bb2[c]);
        float4 hi = make_float4(acc2[4][c] + bb2[c], acc2[5][c] + bb2[c],
                                acc2[6][c] + bb2[c], acc2[7][c] + bb2[c]);
        *(float4*)&hs[(cg * 4 + c) * 68 + rg * 8] = lo;
        *(float4*)&hs[(cg * 4 + c) * 68 + rg * 8 + 4] = hi;
      }
    }
  } else {
    // root joint: h = z_j directly
#pragma unroll
    for (int v = 0; v < 8; ++v) {
      int idx = v * 256 + tid;
      int r = idx >> 5, c4 = idx & 31;
      float4 vz = *(const float4*)&z[(size_t)(row0 + r) * rstride + (size_t)jj * CD + c4 * 4];
      hs[(c4 * 4 + 0) * 68 + r] = vz.x;
      hs[(c4 * 4 + 1) * 68 + r] = vz.y;
      hs[(c4 * 4 + 2) * 68 + r] = vz.z;
      hs[(c4 * 4 + 3) * 68 + r] = vz.w;
    }
  }

  // ================= phase 4: d = ||E||^2 - 2 h.E ; running argmin =========
  float mnv[8]; int mni[8];
#pragma unroll
  for (int r = 0; r < 8; ++r) { mnv[r] = 3.402823e38f; mni[r] = 0; }
  const float* embJ = emb + (size_t)jj * NE * CD;
  const float* nrmJ = nrm + jj * NE;

#pragma unroll 1
  for (int p = 0; p < 4; ++p) {
    __syncthreads();  // hs ready (p=0); es/nsm WAR from previous chunk
    if (tid < 64) {
      *(float4*)&nsm[tid * 4] = *(const float4*)&nrmJ[p * 256 + tid * 4];
    }
    float acc4[8][8];
#pragma unroll
    for (int r = 0; r < 8; ++r)
#pragma unroll
      for (int c = 0; c < 8; ++c) acc4[r][c] = 0.f;

#pragma unroll 1
    for (int kc = 0; kc < 8; ++kc) {
      // stage e chunk [16 dims][256 codes] (coalesced 64B per 4 lanes)
#pragma unroll
      for (int v = 0; v < 4; ++v) {
        int idx = v * 256 + tid;
        int n = idx >> 2, kq = idx & 3;
        float4 ev = *(const float4*)&embJ[(size_t)(p * 256 + n) * CD + kc * 16 + kq * 4];
        es[(kq * 4 + 0) * 260 + n] = ev.x;
        es[(kq * 4 + 1) * 260 + n] = ev.y;
        es[(kq * 4 + 2) * 260 + n] = ev.z;
        es[(kq * 4 + 3) * 260 + n] = ev.w;
      }
      __syncthreads();
#pragma unroll 2
      for (int kk = 0; kk < 16; ++kk) {
        int c = kc * 16 + kk;
        float hr[8], ec[8];
        *(float4*)&hr[0] = *(const float4*)&hs[c * 68 + rg * 8];
        *(float4*)&hr[4] = *(const float4*)&hs[c * 68 + rg * 8 + 4];
        *(float4*)&ec[0] = *(const float4*)&es[kk * 260 + qcA];
        *(float4*)&ec[4] = *(const float4*)&es[kk * 260 + qcB];
#pragma unroll
        for (int r = 0; r < 8; ++r)
#pragma unroll
          for (int c2 = 0; c2 < 8; ++c2)
            acc4[r][c2] += hr[r] * ec[c2];
      }
      __syncthreads();
    }
    // min update, ascending-n order with strict < (first-occurrence ties)
#pragma unroll
    for (int r = 0; r < 8; ++r) {
#pragma unroll
      for (int c2 = 0; c2 < 8; ++c2) {
        int nl = (c2 < 4) ? (qcA + c2) : (qcB + c2 - 4);
        float d = nsm[nl] - 2.f * acc4[r][c2];
        int n = p * 256 + nl;
        if (d < mnv[r]) { mnv[r] = d; mni[r] = n; }
      }
    }
  }

  // cross-lane argmin reduce over the 32-lane col group, tie -> smaller index
#pragma unroll
  for (int r = 0; r < 8; ++r) {
    float mv = mnv[r]; int mi = mni[r];
#pragma unroll
    for (int m = 1; m < 32; m <<= 1) {
      float om = __shfl_xor(mv, m); int oi = __shfl_xor(mi, m);
      if (om < mv || (om == mv && oi < mi)) { mv = om; mi = oi; }
    }
    mnv[r] = mv; mni[r] = mi;
  }

  // gather e, write z_q + indices, accumulate loss
  float lsum = 0.f;
#pragma unroll
  for (int r = 0; r < 8; ++r) {
    int row = rg * 8 + r;
    int id = mni[r];
    const float* erow = embJ + (size_t)id * CD;
    float4 ev = *(const float4*)&erow[cg * 4];
    float h0 = hs[(cg * 4 + 0) * 68 + row];
    float h1 = hs[(cg * 4 + 1) * 68 + row];
    float h2 = hs[(cg * 4 + 2) * 68 + row];
    float h3 = hs[(cg * 4 + 3) * 68 + row];
    float dx = ev.x - h0, dy = ev.y - h1, dz = ev.z - h2, dw = ev.w - h3;
    lsum += dx * dx + dy * dy + dz * dz + dw * dw;
    *(float4*)&zq[(size_t)(row0 + row) * rstride + (size_t)jj * CD + cg * 4] = ev;
    if (cg == 0) idx_out[(size_t)(row0 + row) * NJ + jj] = (float)id;
  }
#pragma unroll
  for (int m = 1; m < 64; m <<= 1) lsum += __shfl_xor(lsum, m);
  if ((tid & 63) == 0) wsum[tid >> 6] = lsum;
  __syncthreads();
  if (tid == 0) partials[pbase + blockIdx.x] = wsum[0] + wsum[1] + wsum[2] + wsum[3];
}

// ---------------------------------------------------------------------------
// deterministic loss reduction
// ---------------------------------------------------------------------------
__global__ __launch_bounds__(256) void loss_reduce(const float* __restrict__ p, int n,
                                                   float* __restrict__ out) {
  __shared__ float ws[4];
  float s = 0.f;
  for (int i = threadIdx.x; i < n; i += 256) s += p[i];
#pragma unroll
  for (int m = 1; m < 64; m <<= 1) s += __shfl_xor(s, m);
  if ((threadIdx.x & 63) == 0) ws[threadIdx.x >> 6] = s;
  __syncthreads();
  if (threadIdx.x == 0)
    out[0] = (ws[0] + ws[1] + ws[2] + ws[3]) * (1.25f / (1048576.f * 32.f));
}

extern "C" void kernel_launch(void* const* d_in, const int* in_sizes, int n_in,
                              void* d_out, int out_size, void* d_ws, size_t ws_size,
                              hipStream_t stream) {
  const float* z = (const float*)d_in[0];
  const float* emb = (const float*)d_in[1];
  const float* W1 = (const float*)d_in[2];
  const float* b1 = (const float*)d_in[3];
  const float* lng = (const float*)d_in[4];
  const float* lnb = (const float*)d_in[5];
  const float* W2 = (const float*)d_in[6];
  const float* b2 = (const float*)d_in[7];

  float* zq = (float*)d_out;
  float* loss = zq + (size_t)ROWS * NJ * CD;  // 33,554,432
  float* idxo = loss + 1;

  float* nrm = (float*)d_ws;           // NJ*NE floats
  float* partials = nrm + NJ * NE;     // 32*128 floats

  norms_kernel<<<NJ * NE * 4 / 256, 256, 0, stream>>>(emb, nrm);

  static const Lv levels[11] = {
      {1, {0, 0, 0, 0, 0}, {-1, 0, 0, 0, 0}},
      {3, {1, 6, 11, 0, 0}, {0, 0, 0, 0, 0}},
      {3, {2, 7, 12, 0, 0}, {1, 6, 11, 0, 0}},
      {5, {3, 8, 13, 16, 24}, {2, 7, 12, 12, 12}},
      {5, {4, 9, 14, 17, 25}, {3, 8, 13, 16, 24}},
      {5, {5, 10, 15, 18, 26}, {4, 9, 14, 17, 25}},
      {2, {19, 27, 0, 0, 0}, {18, 26, 0, 0, 0}},
      {2, {20, 28, 0, 0, 0}, {19, 27, 0, 0, 0}},
      {2, {21, 29, 0, 0, 0}, {20, 28, 0, 0, 0}},
      {2, {22, 30, 0, 0, 0}, {21, 29, 0, 0, 0}},
      {2, {23, 31, 0, 0, 0}, {22, 30, 0, 0, 0}},
  };

  int pbase = 0;
  for (int L = 0; L < 11; ++L) {
    fused_level<<<levels[L].nj * BPJ, 256, 0, stream>>>(
        z, emb, W1, b1, lng, lnb, W2, b2, nrm, zq, idxo, partials, levels[L], pbase);
    pbase += levels[L].nj * BPJ;
  }
  loss_reduce<<<1, 256, 0, stream>>>(partials, pbase, loss);
}

// Round 5
// 1944.347 us; speedup vs baseline: 1.7391x; 1.0546x over previous
//
#include <hip/hip_runtime.h>

#define NJ 32
#define NE 1024
#define CD 128
#define HID 256
#define ROWS 8192
#define RB 64
#define BPJ (ROWS / RB)   // 128 blocks per joint

struct Lv { int nj; int j[5]; int p[5]; };

// ---------------------------------------------------------------------------
// codebook norms: nrm[j*NE+n] = sum_c emb[j][n][c]^2   (4 lanes per code row)
// ---------------------------------------------------------------------------
__global__ __launch_bounds__(256) void norms_kernel(const float* __restrict__ emb,
                                                    float* __restrict__ nrm) {
  int gid = blockIdx.x * 256 + threadIdx.x;
  int n = gid >> 2, l = gid & 3;           // n in [0, NJ*NE)
  const float* row = emb + (size_t)n * CD;
  float s = 0.f;
#pragma unroll
  for (int i = 0; i < 8; ++i) {
    float4 v = *(const float4*)&row[(l + 4 * i) * 4];
    s += v.x * v.x + v.y * v.y + v.z * v.z + v.w * v.w;
  }
  s += __shfl_xor(s, 1);
  s += __shfl_xor(s, 2);
  if (l == 0) nrm[n] = s;
}

// ---------------------------------------------------------------------------
// fused per-level kernel, RB=64 rows per block, 8x8 register tiles
// (phase 4: 8x16 — 512-code chunks, halves LDS bytes/FLOP in the hot GEMM).
// thread layout: rg = tid>>5 (8 row-groups of 8 rows), cg = tid&31.
// col/code ownership (contiguous-16B-chunk, conflict-free): u=cg&15, b=cg>>4;
//   thread owns cols/codes {b*128+u*4 .. +3} and {b*128+64+u*4 .. +3}
//   (phase 4 additionally +256 of each within a 512-code chunk).
// LDS (floats): hs [0,8704) = h tile [128 dims][68 rows]
//               S  [8704,19520) scratch:
//                 phase1: xs [32][68] @S, ws1 [32][264] @S+2176
//                 phase3: as_ [128][68] @S, ws2 [16][132] @S+8704
//                 phase4: es [16][516] @S, nsm [512] @S+8256
// ---------------------------------------------------------------------------
__global__ __launch_bounds__(256) void fused_level(
    const float* __restrict__ z, const float* __restrict__ emb,
    const float* __restrict__ W1, const float* __restrict__ b1,
    const float* __restrict__ lng, const float* __restrict__ lnb,
    const float* __restrict__ W2, const float* __restrict__ b2,
    const float* __restrict__ nrm,
    float* __restrict__ zq, float* __restrict__ idx_out,
    float* __restrict__ partials, Lv lv, int pbase) {
  __shared__ __align__(16) float smem[19520];
  __shared__ float wsum[4];
  float* hs  = smem;
  float* S   = smem + 8704;
  float* xs  = S;
  float* ws1 = S + 2176;
  float* as_ = S;
  float* ws2 = S + 8704;
  float* es  = S;
  float* nsm = S + 8256;

  const int tid = threadIdx.x;
  const int rg = tid >> 5, cg = tid & 31;
  const int u = cg & 15;                       // round-1 "tj"
  const int qcA = (cg >> 4) * 128 + u * 4;     // first owned quad (col/code)
  const int qcB = qcA + 64;                    // second owned quad (col/code)
  const int jl = blockIdx.x / BPJ;
  const int row0 = (blockIdx.x % BPJ) * RB;
  const int jj = lv.j[jl], pj = lv.p[jl];
  const size_t rstride = (size_t)NJ * CD;

  if (pj >= 0) {
    // ================= phase 1: a1 = [e_parent | z_j] @ W1 =================
    float acc1[8][8];
#pragma unroll
    for (int r = 0; r < 8; ++r)
#pragma unroll
      for (int c = 0; c < 8; ++c) acc1[r][c] = 0.f;

#pragma unroll 1
    for (int ks = 0; ks < 8; ++ks) {
      // stage x chunk [32 k][64 rows] (transposed into xs)
#pragma unroll
      for (int uu = 0; uu < 2; ++uu) {
        int idx = uu * 256 + tid;
        int r = idx >> 3, kq = idx & 7;
        const float* src = (ks < 4)
            ? (zq + (size_t)(row0 + r) * rstride + (size_t)pj * CD + (ks * 32 + kq * 4))
            : (z  + (size_t)(row0 + r) * rstride + (size_t)jj * CD + (ks * 32 - 128 + kq * 4));
        float4 v = *(const float4*)src;
        xs[(kq * 4 + 0) * 68 + r] = v.x;
        xs[(kq * 4 + 1) * 68 + r] = v.y;
        xs[(kq * 4 + 2) * 68 + r] = v.z;
        xs[(kq * 4 + 3) * 68 + r] = v.w;
      }
      // stage W1 chunk [32 k][256 cols]
#pragma unroll
      for (int v8 = 0; v8 < 8; ++v8) {
        int idx = v8 * 256 + tid;
        int k = idx >> 6, c4 = idx & 63;
        *(float4*)&ws1[k * 264 + c4 * 4] =
            *(const float4*)&W1[(size_t)(ks * 32 + k) * HID + c4 * 4];
      }
      __syncthreads();
#pragma unroll 2
      for (int kk = 0; kk < 32; ++kk) {
        float xr[8], wc[8];
        *(float4*)&xr[0] = *(const float4*)&xs[kk * 68 + rg * 8];
        *(float4*)&xr[4] = *(const float4*)&xs[kk * 68 + rg * 8 + 4];
        *(float4*)&wc[0] = *(const float4*)&ws1[kk * 264 + qcA];
        *(float4*)&wc[4] = *(const float4*)&ws1[kk * 264 + qcB];
#pragma unroll
        for (int r = 0; r < 8; ++r)
#pragma unroll
          for (int c = 0; c < 8; ++c)
            acc1[r][c] += xr[r] * wc[c];
      }
      __syncthreads();
    }

    // ====== phase 2: +b1, LayerNorm, ReLU — round-1 bit-exact tree =========
    {
      float bb[8], gg[8], be[8];
      *(float4*)&bb[0] = *(const float4*)&b1[qcA];
      *(float4*)&bb[4] = *(const float4*)&b1[qcB];
      *(float4*)&gg[0] = *(const float4*)&lng[qcA];
      *(float4*)&gg[4] = *(const float4*)&lng[qcB];
      *(float4*)&be[0] = *(const float4*)&lnb[qcA];
      *(float4*)&be[4] = *(const float4*)&lnb[qcB];
#pragma unroll
      for (int r = 0; r < 8; ++r) {
        // b0 lane (cg<16): chain over g=0,1 quads starting from 0.
        float s0 = 0.f, q0 = 0.f;
#pragma unroll
        for (int j = 0; j < 8; ++j) {
          float v = acc1[r][j] + bb[j];
          acc1[r][j] = v;
          s0 += v; q0 += v * v;
        }
        // hand partial to b1 partner; b1 continues the chain over g=2,3.
        float si = __shfl_xor(s0, 16), qi = __shfl_xor(q0, 16);
        float s1 = si, q1 = qi;
#pragma unroll
        for (int j = 0; j < 8; ++j) {
          float v = acc1[r][j];
          s1 += v; q1 += v * v;
        }
        // round-1 butterfly over the 16 "tj" lanes (valid in b1 lanes)
#pragma unroll
        for (int m = 1; m < 16; m <<= 1) {
          s1 += __shfl_xor(s1, m); q1 += __shfl_xor(q1, m);
        }
        float s2 = __shfl_xor(s1, 16), q2 = __shfl_xor(q1, 16);
        float Sx = (cg & 16) ? s1 : s2;
        float Qx = (cg & 16) ? q1 : q2;
        float mu = Sx * (1.f / HID);
        float va = Qx * (1.f / HID) - mu * mu;
        float iv = 1.f / sqrtf(va + 1e-5f);
#pragma unroll
        for (int j = 0; j < 8; ++j) {
          float a = (acc1[r][j] - mu) * iv * gg[j] + be[j];
          acc1[r][j] = fmaxf(a, 0.f);
        }
      }
    }

    // ================= phase 3: h = a @ W2 + b2 (two 128-k halves) =========
    float acc2[8][4];
#pragma unroll
    for (int r = 0; r < 8; ++r)
#pragma unroll
      for (int c = 0; c < 4; ++c) acc2[r][c] = 0.f;

#pragma unroll 1
    for (int half = 0; half < 2; ++half) {
      __syncthreads();
      if ((cg >> 4) == half) {
#pragma unroll
        for (int j = 0; j < 8; ++j) {
          int kl = (j >> 2) * 64 + u * 4 + (j & 3);
          *(float4*)&as_[kl * 68 + rg * 8] =
              make_float4(acc1[0][j], acc1[1][j], acc1[2][j], acc1[3][j]);
          *(float4*)&as_[kl * 68 + rg * 8 + 4] =
              make_float4(acc1[4][j], acc1[5][j], acc1[6][j], acc1[7][j]);
        }
      }
      __syncthreads();
#pragma unroll 1
      for (int kc = 0; kc < 8; ++kc) {
#pragma unroll
        for (int v = 0; v < 2; ++v) {
          int idx = v * 256 + tid;
          int k = idx >> 5, c4 = idx & 31;
          *(float4*)&ws2[k * 132 + c4 * 4] =
              *(const float4*)&W2[(size_t)(half * 128 + kc * 16 + k) * CD + c4 * 4];
        }
        __syncthreads();
#pragma unroll 2
        for (int kk = 0; kk < 16; ++kk) {
          float ar[8], wc2[4];
          *(float4*)&ar[0] = *(const float4*)&as_[(kc * 16 + kk) * 68 + rg * 8];
          *(float4*)&ar[4] = *(const float4*)&as_[(kc * 16 + kk) * 68 + rg * 8 + 4];
          *(float4*)&wc2[0] = *(const float4*)&ws2[kk * 132 + cg * 4];
#pragma unroll
          for (int r = 0; r < 8; ++r)
#pragma unroll
            for (int c = 0; c < 4; ++c)
              acc2[r][c] += ar[r] * wc2[c];
        }
        __syncthreads();
      }
    }
    {
      float4 bv = *(const float4*)&b2[cg * 4];
      float bb2[4] = {bv.x, bv.y, bv.z, bv.w};
#pragma unroll
      for (int c = 0; c < 4; ++c) {
        float4 lo = make_float4(acc2[0][c] + bb2[c], acc2[1][c] + bb2[c],
                                acc2[2][c] + bb2[c], acc2[3][c] + bb2[c]);
        float4 hi = make_float4(acc2[4][c] + bb2[c], acc2[5][c] + bb2[c],
                                acc2[6][c] + bb2[c], acc2[7][c] + bb2[c]);
        *(float4*)&hs[(cg * 4 + c) * 68 + rg * 8] = lo;
        *(float4*)&hs[(cg * 4 + c) * 68 + rg * 8 + 4] = hi;
      }
    }
  } else {
    // root joint: h = z_j directly
#pragma unroll
    for (int v = 0; v < 8; ++v) {
      int idx = v * 256 + tid;
      int r = idx >> 5, c4 = idx & 31;
      float4 vz = *(const float4*)&z[(size_t)(row0 + r) * rstride + (size_t)jj * CD + c4 * 4];
      hs[(c4 * 4 + 0) * 68 + r] = vz.x;
      hs[(c4 * 4 + 1) * 68 + r] = vz.y;
      hs[(c4 * 4 + 2) * 68 + r] = vz.z;
      hs[(c4 * 4 + 3) * 68 + r] = vz.w;
    }
  }

  // ====== phase 4: d = ||E||^2 - 2 h.E ; 8x16 tiles, 512-code chunks ======
  float mnv[8]; int mni[8];
#pragma unroll
  for (int r = 0; r < 8; ++r) { mnv[r] = 3.402823e38f; mni[r] = 0; }
  const float* embJ = emb + (size_t)jj * NE * CD;
  const float* nrmJ = nrm + jj * NE;

#pragma unroll 1
  for (int p = 0; p < 2; ++p) {
    __syncthreads();  // hs ready (p=0); es/nsm WAR from previous chunk
    if (tid < 128) {
      *(float4*)&nsm[tid * 4] = *(const float4*)&nrmJ[p * 512 + tid * 4];
    }
    float acc4[8][16];
#pragma unroll
    for (int r = 0; r < 8; ++r)
#pragma unroll
      for (int c = 0; c < 16; ++c) acc4[r][c] = 0.f;

#pragma unroll 1
    for (int kc = 0; kc < 8; ++kc) {
      // stage e chunk [16 dims][512 codes] (coalesced 64B per 4 lanes)
#pragma unroll
      for (int v = 0; v < 8; ++v) {
        int idx = v * 256 + tid;
        int n = idx >> 2, kq = idx & 3;
        float4 ev = *(const float4*)&embJ[(size_t)(p * 512 + n) * CD + kc * 16 + kq * 4];
        es[(kq * 4 + 0) * 516 + n] = ev.x;
        es[(kq * 4 + 1) * 516 + n] = ev.y;
        es[(kq * 4 + 2) * 516 + n] = ev.z;
        es[(kq * 4 + 3) * 516 + n] = ev.w;
      }
      __syncthreads();
#pragma unroll 2
      for (int kk = 0; kk < 16; ++kk) {
        int c = kc * 16 + kk;
        float hr[8], ec[16];
        *(float4*)&hr[0] = *(const float4*)&hs[c * 68 + rg * 8];
        *(float4*)&hr[4] = *(const float4*)&hs[c * 68 + rg * 8 + 4];
        *(float4*)&ec[0]  = *(const float4*)&es[kk * 516 + qcA];
        *(float4*)&ec[4]  = *(const float4*)&es[kk * 516 + qcB];
        *(float4*)&ec[8]  = *(const float4*)&es[kk * 516 + 256 + qcA];
        *(float4*)&ec[12] = *(const float4*)&es[kk * 516 + 256 + qcB];
#pragma unroll
        for (int r = 0; r < 8; ++r)
#pragma unroll
          for (int c2 = 0; c2 < 16; ++c2)
            acc4[r][c2] += hr[r] * ec[c2];
      }
      __syncthreads();
    }
    // min update, ascending-n order with strict < (first-occurrence ties);
    // per-thread (n,d) visit sequence identical to the 256-chunk version.
#pragma unroll
    for (int r = 0; r < 8; ++r) {
#pragma unroll
      for (int q = 0; q < 4; ++q) {
        int o = ((q & 1) ? qcB : qcA) + (q >> 1) * 256;
#pragma unroll
        for (int cc = 0; cc < 4; ++cc) {
          int nl = o + cc;
          float d = nsm[nl] - 2.f * acc4[r][q * 4 + cc];
          int n = p * 512 + nl;
          if (d < mnv[r]) { mnv[r] = d; mni[r] = n; }
        }
      }
    }
  }

  // cross-lane argmin reduce over the 32-lane col group, tie -> smaller index
#pragma unroll
  for (int r = 0; r < 8; ++r) {
    float mv = mnv[r]; int mi = mni[r];
#pragma unroll
    for (int m = 1; m < 32; m <<= 1) {
      float om = __shfl_xor(mv, m); int oi = __shfl_xor(mi, m);
      if (om < mv || (om == mv && oi < mi)) { mv = om; mi = oi; }
    }
    mnv[r] = mv; mni[r] = mi;
  }

  // gather e, write z_q + indices, accumulate loss
  float lsum = 0.f;
#pragma unroll
  for (int r = 0; r < 8; ++r) {
    int row = rg * 8 + r;
    int id = mni[r];
    const float* erow = embJ + (size_t)id * CD;
    float4 ev = *(const float4*)&erow[cg * 4];
    float h0 = hs[(cg * 4 + 0) * 68 + row];
    float h1 = hs[(cg * 4 + 1) * 68 + row];
    float h2 = hs[(cg * 4 + 2) * 68 + row];
    float h3 = hs[(cg * 4 + 3) * 68 + row];
    float dx = ev.x - h0, dy = ev.y - h1, dz = ev.z - h2, dw = ev.w - h3;
    lsum += dx * dx + dy * dy + dz * dz + dw * dw;
    *(float4*)&zq[(size_t)(row0 + row) * rstride + (size_t)jj * CD + cg * 4] = ev;
    if (cg == 0) idx_out[(size_t)(row0 + row) * NJ + jj] = (float)id;
  }
#pragma unroll
  for (int m = 1; m < 64; m <<= 1) lsum += __shfl_xor(lsum, m);
  if ((tid & 63) == 0) wsum[tid >> 6] = lsum;
  __syncthreads();
  if (tid == 0) partials[pbase + blockIdx.x] = wsum[0] + wsum[1] + wsum[2] + wsum[3];
}

// ---------------------------------------------------------------------------
// deterministic loss reduction
// ---------------------------------------------------------------------------
__global__ __launch_bounds__(256) void loss_reduce(const float* __restrict__ p, int n,
                                                   float* __restrict__ out) {
  __shared__ float ws[4];
  float s = 0.f;
  for (int i = threadIdx.x; i < n; i += 256) s += p[i];
#pragma unroll
  for (int m = 1; m < 64; m <<= 1) s += __shfl_xor(s, m);
  if ((threadIdx.x & 63) == 0) ws[threadIdx.x >> 6] = s;
  __syncthreads();
  if (threadIdx.x == 0)
    out[0] = (ws[0] + ws[1] + ws[2] + ws[3]) * (1.25f / (1048576.f * 32.f));
}

extern "C" void kernel_launch(void* const* d_in, const int* in_sizes, int n_in,
                              void* d_out, int out_size, void* d_ws, size_t ws_size,
                              hipStream_t stream) {
  const float* z = (const float*)d_in[0];
  const float* emb = (const float*)d_in[1];
  const float* W1 = (const float*)d_in[2];
  const float* b1 = (const float*)d_in[3];
  const float* lng = (const float*)d_in[4];
  const float* lnb = (const float*)d_in[5];
  const float* W2 = (const float*)d_in[6];
  const float* b2 = (const float*)d_in[7];

  float* zq = (float*)d_out;
  float* loss = zq + (size_t)ROWS * NJ * CD;  // 33,554,432
  float* idxo = loss + 1;

  float* nrm = (float*)d_ws;           // NJ*NE floats
  float* partials = nrm + NJ * NE;     // 32*128 floats

  norms_kernel<<<NJ * NE * 4 / 256, 256, 0, stream>>>(emb, nrm);

  static const Lv levels[11] = {
      {1, {0, 0, 0, 0, 0}, {-1, 0, 0, 0, 0}},
      {3, {1, 6, 11, 0, 0}, {0, 0, 0, 0, 0}},
      {3, {2, 7, 12, 0, 0}, {1, 6, 11, 0, 0}},
      {5, {3, 8, 13, 16, 24}, {2, 7, 12, 12, 12}},
      {5, {4, 9, 14, 17, 25}, {3, 8, 13, 16, 24}},
      {5, {5, 10, 15, 18, 26}, {4, 9, 14, 17, 25}},
      {2, {19, 27, 0, 0, 0}, {18, 26, 0, 0, 0}},
      {2, {20, 28, 0, 0, 0}, {19, 27, 0, 0, 0}},
      {2, {21, 29, 0, 0, 0}, {20, 28, 0, 0, 0}},
      {2, {22, 30, 0, 0, 0}, {21, 29, 0, 0, 0}},
      {2, {23, 31, 0, 0, 0}, {22, 30, 0, 0, 0}},
  };

  int pbase = 0;
  for (int L = 0; L < 11; ++L) {
    fused_level<<<levels[L].nj * BPJ, 256, 0, stream>>>(
        z, emb, W1, b1, lng, lnb, W2, b2, nrm, zq, idxo, partials, levels[L], pbase);
    pbase += levels[L].nj * BPJ;
  }
  loss_reduce<<<1, 256, 0, stream>>>(partials, pbase, loss);
}